// Round 7
// baseline (727.938 us; speedup 1.0000x reference)
//
#include <hip/hip_runtime.h>
#include <math.h>

typedef __bf16 bf16;
typedef __bf16 bf16x4 __attribute__((ext_vector_type(4)));
typedef __bf16 bf16x8 __attribute__((ext_vector_type(8)));
typedef float floatx4 __attribute__((ext_vector_type(4)));
typedef int intx4 __attribute__((ext_vector_type(4)));

#define MFMA16(a, b, c) __builtin_amdgcn_mfma_f32_16x16x32_bf16((a), (b), (c), 0, 0, 0)

static constexpr int NROWS = 8192;
static constexpr int DCH = 512;
static constexpr int NSPLIT = 8;                 // K-dim split (== XCD count)
static constexpr int KRANGE = NROWS / NSPLIT;    // 1024 K-rows per block
static constexpr int KTILE = 64;                 // K rows per iteration
static constexpr int NITER = KRANGE / KTILE;     // 16
// 1/sqrt(512) * log2(e): folded into Q so phase A is exp2f(s) directly
static constexpr float PRESCALE = 0.0637587130f;

// Blocked layout: X_blk[r/16][c/32][16][32] bf16 — 16x32 tile = 1KB contiguous;
// MFMA frag load = lane 16B at tile + lm*32 + (lane>>4)*8, fully coalesced.

// ---------------- merged fp32 -> bf16 blocked convert (8 segments) ----------------
struct CvtArgs {
    const float* src[8];
    bf16* dst[8];
    int C[8];
    int n8[8];
    float scale[8];
};

__global__ void cvt_all_kernel(CvtArgs a) {
    int seg = blockIdx.y;
    int i = blockIdx.x * blockDim.x + threadIdx.x;
    if (i >= a.n8[seg]) return;
    const float* __restrict__ in = a.src[seg];
    bf16* __restrict__ out = a.dst[seg];
    int C = a.C[seg];
    float s = a.scale[seg];
    int c8 = i % (C >> 3);
    int r = i / (C >> 3);
    float4 v0 = ((const float4*)in)[i * 2];
    float4 v1 = ((const float4*)in)[i * 2 + 1];
    bf16x8 o;
    o[0] = (bf16)(v0.x * s); o[1] = (bf16)(v0.y * s);
    o[2] = (bf16)(v0.z * s); o[3] = (bf16)(v0.w * s);
    o[4] = (bf16)(v1.x * s); o[5] = (bf16)(v1.y * s);
    o[6] = (bf16)(v1.z * s); o[7] = (bf16)(v1.w * s);
    int nkb = C >> 5;
    size_t e = ((size_t)(r >> 4) * nkb + (c8 >> 2)) * 512 + (r & 15) * 32 + (c8 & 3) * 8;
    *(bf16x8*)(out + e) = o;
}

// ---------------- projection GEMM: Q / K1 / K2 / Vt via blockIdx.z ----------------
__launch_bounds__(256)
__global__ void proj_gemm(const bf16* __restrict__ spb, const bf16* __restrict__ om1b,
                          const bf16* __restrict__ om2b,
                          const bf16* __restrict__ qwb, const bf16* __restrict__ k1wb,
                          const bf16* __restrict__ k2wb, const bf16* __restrict__ vwb,
                          const float* __restrict__ q_b, const float* __restrict__ k1_b,
                          const float* __restrict__ k2_b, const float* __restrict__ v_b,
                          bf16* __restrict__ Q, bf16* __restrict__ K1, bf16* __restrict__ K2,
                          bf16* __restrict__ Vt) {
    const bf16* As[3] = {nullptr, nullptr, nullptr};
    int wofs[3] = {0, 0, 0};
    int nchunk = 1, ldw = 512, mode = 0;   // 0: blocked out, 1: blocked-trans out (Vt)
    float bscale = 1.f;
    const bf16* W = nullptr;
    const float* bias = nullptr;
    bf16* out = nullptr;
    switch (blockIdx.z) {
        case 0: As[0] = spb;  W = qwb;  bias = q_b;  out = Q;  bscale = PRESCALE; break;
        case 1: As[0] = om1b; W = k1wb; bias = k1_b; out = K1; break;
        case 2: As[0] = om2b; W = k2wb; bias = k2_b; out = K2; break;
        default: As[0] = spb; As[1] = om1b; As[2] = om2b; nchunk = 3; W = vwb; ldw = 1536;
                 wofs[1] = 512; wofs[2] = 1024; bias = v_b; out = Vt; mode = 1; break;
    }

    const int lane = threadIdx.x & 63;
    const int wv = threadIdx.x >> 6;
    const int m0 = blockIdx.y * 128 + (wv >> 1) * 64;
    const int n0 = blockIdx.x * 128 + (wv & 1) * 64;
    const int lm = lane & 15;
    const int lk8 = (lane >> 4) * 8;
    const int r0 = (lane >> 4) * 4;
    const int nkbW = ldw >> 5;

    floatx4 acc[4][4];
    #pragma unroll
    for (int mt = 0; mt < 4; ++mt)
        #pragma unroll
        for (int nt = 0; nt < 4; ++nt)
            acc[mt][nt] = (floatx4){0.f, 0.f, 0.f, 0.f};

    for (int c = 0; c < nchunk; ++c) {
        const bf16* __restrict__ A = As[c];
        const int wo = wofs[c];
        #pragma unroll 2
        for (int kk = 0; kk < 512; kk += 32) {
            bf16x8 a[4], b[4];
            #pragma unroll
            for (int mt = 0; mt < 4; ++mt)
                a[mt] = *(const bf16x8*)(A + ((size_t)((m0 + mt * 16) >> 4) * 16 + (kk >> 5)) * 512
                                           + lm * 32 + lk8);
            #pragma unroll
            for (int nt = 0; nt < 4; ++nt)
                b[nt] = *(const bf16x8*)(W + ((size_t)((n0 + nt * 16) >> 4) * nkbW + ((wo + kk) >> 5)) * 512
                                           + lm * 32 + lk8);
            #pragma unroll
            for (int mt = 0; mt < 4; ++mt)
                #pragma unroll
                for (int nt = 0; nt < 4; ++nt)
                    acc[mt][nt] = MFMA16(a[mt], b[nt], acc[mt][nt]);
        }
    }

    #pragma unroll
    for (int mt = 0; mt < 4; ++mt)
        #pragma unroll
        for (int nt = 0; nt < 4; ++nt)
            #pragma unroll
            for (int i = 0; i < 4; ++i) {
                int m = m0 + mt * 16 + r0 + i;
                int n = n0 + nt * 16 + lm;
                float v = acc[mt][nt][i] + bias[n] * bscale;
                if (mode == 0)
                    out[((size_t)(m >> 4) * 16 + (n >> 5)) * 512 + (m & 15) * 32 + (n & 31)] = (bf16)v;
                else
                    out[((size_t)(n >> 4) * 256 + (m >> 5)) * 512 + (n & 15) * 32 + (m & 31)] = (bf16)v;
            }
}

// ---------------- conf GEMM + gate fused ----------------
// Z1 = sp@W0' + om1@W1' + b ; Z2 = sp@W0' + om2@W1' + b  (W0 = c1w[:,:512], W1 = c1w[:,512:])
// Shared term sp@W0 computed ONCE. Epilogue: w1 = sigmoid(sigmoid(z1)-sigmoid(z2)) -> bf16.
__launch_bounds__(256)
__global__ void conf_gemm(const bf16* __restrict__ spb, const bf16* __restrict__ om1b,
                          const bf16* __restrict__ om2b, const bf16* __restrict__ c1wb,
                          const float* __restrict__ c1_b, bf16* __restrict__ W1out) {
    const int lane = threadIdx.x & 63;
    const int wv = threadIdx.x >> 6;
    const int m0 = blockIdx.y * 128 + (wv >> 1) * 64;
    const int n0 = blockIdx.x * 128 + (wv & 1) * 64;
    const int lm = lane & 15;
    const int lk8 = (lane >> 4) * 8;
    const int r0 = (lane >> 4) * 4;

    floatx4 acc1[4][4], acc2[4][4];
    {   // phase 1: shared sp @ W0 into acc1
        #pragma unroll
        for (int mt = 0; mt < 4; ++mt)
            #pragma unroll
            for (int nt = 0; nt < 4; ++nt)
                acc1[mt][nt] = (floatx4){0.f, 0.f, 0.f, 0.f};
        #pragma unroll 2
        for (int kk = 0; kk < 512; kk += 32) {
            bf16x8 a[4], b[4];
            #pragma unroll
            for (int mt = 0; mt < 4; ++mt)
                a[mt] = *(const bf16x8*)(spb + ((size_t)((m0 + mt * 16) >> 4) * 16 + (kk >> 5)) * 512
                                             + lm * 32 + lk8);
            #pragma unroll
            for (int nt = 0; nt < 4; ++nt)
                b[nt] = *(const bf16x8*)(c1wb + ((size_t)((n0 + nt * 16) >> 4) * 32 + (kk >> 5)) * 512
                                              + lm * 32 + lk8);
            #pragma unroll
            for (int mt = 0; mt < 4; ++mt)
                #pragma unroll
                for (int nt = 0; nt < 4; ++nt)
                    acc1[mt][nt] = MFMA16(a[mt], b[nt], acc1[mt][nt]);
        }
    }
    // duplicate shared term
    #pragma unroll
    for (int mt = 0; mt < 4; ++mt)
        #pragma unroll
        for (int nt = 0; nt < 4; ++nt)
            acc2[mt][nt] = acc1[mt][nt];

    // phase 2: om1@W1 -> acc1, om2@W1 -> acc2 (B frags shared)
    #pragma unroll 2
    for (int kk = 0; kk < 512; kk += 32) {
        bf16x8 a1[4], a2[4], b[4];
        #pragma unroll
        for (int mt = 0; mt < 4; ++mt) {
            size_t ao = ((size_t)((m0 + mt * 16) >> 4) * 16 + (kk >> 5)) * 512 + lm * 32 + lk8;
            a1[mt] = *(const bf16x8*)(om1b + ao);
            a2[mt] = *(const bf16x8*)(om2b + ao);
        }
        #pragma unroll
        for (int nt = 0; nt < 4; ++nt)
            b[nt] = *(const bf16x8*)(c1wb + ((size_t)((n0 + nt * 16) >> 4) * 32 + 16 + (kk >> 5)) * 512
                                          + lm * 32 + lk8);
        #pragma unroll
        for (int mt = 0; mt < 4; ++mt)
            #pragma unroll
            for (int nt = 0; nt < 4; ++nt) {
                acc1[mt][nt] = MFMA16(a1[mt], b[nt], acc1[mt][nt]);
                acc2[mt][nt] = MFMA16(a2[mt], b[nt], acc2[mt][nt]);
            }
    }

    #pragma unroll
    for (int mt = 0; mt < 4; ++mt)
        #pragma unroll
        for (int nt = 0; nt < 4; ++nt)
            #pragma unroll
            for (int i = 0; i < 4; ++i) {
                int m = m0 + mt * 16 + r0 + i;
                int n = n0 + nt * 16 + lm;
                float bz = c1_b[n];
                float g1 = 1.f / (1.f + __expf(-(acc1[mt][nt][i] + bz)));
                float g2 = 1.f / (1.f + __expf(-(acc2[mt][nt][i] + bz)));
                W1out[(size_t)m * 512 + n] = (bf16)(1.f / (1.f + __expf(-(g1 - g2))));
            }
}

// ---------------- fused dual attention ----------------
// Block (qb, split=bid&7, XCD-pinned): q rows [qb*32,+32), K rows [split*1024,+1024).
// Iter body is B(it) FIRST (operands ready at barrier), then A(it+1) (K-load latency
// overlaps B's MFMAs), then one barrier. Opart stores nontemporal (don't evict pinned K/Vt).
__launch_bounds__(512, 4)
__global__ void attn_kernel(const bf16* __restrict__ Q, const bf16* __restrict__ K1g,
                            const bf16* __restrict__ K2g, const bf16* __restrict__ Vt,
                            bf16* __restrict__ Opart, float* __restrict__ Lpart) {
    __shared__ bf16 Qs[2 * 16 * 512];        // 32 KB; reused as epilogue staging
    __shared__ bf16 P[2 * 2 * 2 * 2 * 512];  // [buf][attn][mt][kb2][16][32] = 16 KB
    __shared__ float lsum[2][32];

    const int tid = threadIdx.x;
    const int lane = tid & 63;
    const int wv = tid >> 6;                 // 0..7
    const int bid = blockIdx.x;
    const int split = bid & 7;
    const int qb = bid >> 3;
    const int q0 = qb * 32;
    const int k0 = split * KRANGE;
    const int lm = lane & 15;
    const int lk8 = (lane >> 4) * 8;
    const int r0 = (lane >> 4) * 4;
    const int ciq8 = ((lane >> 4) ^ ((lm >> 1) & 3)) * 8;  // swizzled LDS frag chunk

    // stage Q tile (2 blocked super-rows = 32 KB contiguous), swizzle into LDS
    {
        const bf16* Qg = Q + (size_t)(q0 >> 4) * (16 * 512);
        #pragma unroll
        for (int j = 0; j < 4; ++j) {
            int ch = tid + 512 * j;
            bf16x8 v = *(const bf16x8*)(Qg + ch * 8);
            int r = (ch >> 2) & 15;
            int ci = ch & 3;
            int dst = (ch & ~3) * 8 + (ci ^ ((r >> 1) & 3)) * 8;
            *(bf16x8*)(Qs + dst) = v;
        }
    }
    if (tid < 64) lsum[tid >> 5][tid & 31] = 0.f;
    __syncthreads();

    const int pa_a = wv & 1;                 // attention index for phase A
    const int pa_ns = wv >> 1;               // 16-row K slice (0..3) within 64-row tile
    const bf16* __restrict__ Kg = pa_a ? K2g : K1g;
    const int d0 = wv * 64;                  // phase-B d-slice

    floatx4 O[2][2][4];                      // [attn][mt][nt]
    #pragma unroll
    for (int a2 = 0; a2 < 2; ++a2)
        #pragma unroll
        for (int mt = 0; mt < 2; ++mt)
            #pragma unroll
            for (int nt = 0; nt < 4; ++nt)
                O[a2][mt][nt] = (floatx4){0.f, 0.f, 0.f, 0.f};

    float lrs[2][4] = {{0.f, 0.f, 0.f, 0.f}, {0.f, 0.f, 0.f, 0.f}};

    auto phaseA = [&](int kt, int buf) {
        floatx4 sE[2], sO[2];
        #pragma unroll
        for (int mt = 0; mt < 2; ++mt) {
            sE[mt] = (floatx4){0.f, 0.f, 0.f, 0.f};
            sO[mt] = (floatx4){0.f, 0.f, 0.f, 0.f};
        }
        const bf16* Kp = Kg + ((size_t)((kt >> 4) + pa_ns) * 16) * 512 + lm * 32 + lk8;
        #pragma unroll
        for (int kb = 0; kb < 16; kb += 2) {
            bf16x8 b0 = *(const bf16x8*)(Kp + kb * 512);
            bf16x8 b1 = *(const bf16x8*)(Kp + (kb + 1) * 512);
            bf16x8 a00 = *(const bf16x8*)(Qs + kb * 512 + lm * 32 + ciq8);
            bf16x8 a10 = *(const bf16x8*)(Qs + (16 + kb) * 512 + lm * 32 + ciq8);
            bf16x8 a01 = *(const bf16x8*)(Qs + (kb + 1) * 512 + lm * 32 + ciq8);
            bf16x8 a11 = *(const bf16x8*)(Qs + (17 + kb) * 512 + lm * 32 + ciq8);
            sE[0] = MFMA16(a00, b0, sE[0]);
            sE[1] = MFMA16(a10, b0, sE[1]);
            sO[0] = MFMA16(a01, b1, sO[0]);
            sO[1] = MFMA16(a11, b1, sO[1]);
        }
        const int kb2 = pa_ns >> 1;
        const int cb = (pa_ns & 1) * 2;      // 16B-chunk base within 32-col tile
        #pragma unroll
        for (int mt = 0; mt < 2; ++mt) {
            floatx4 s = sE[mt] + sO[mt];
            bf16* pt = P + ((((buf * 2 + pa_a) * 2 + mt) * 2 + kb2) * 512);
            #pragma unroll
            for (int i = 0; i < 4; ++i) {
                float e = exp2f(s[i]);       // Q pre-scaled: exp(logit/sqrt(512))
                int r = r0 + i;
                int ci = (cb + (lm >> 3)) ^ ((r >> 1) & 3);
                pt[r * 32 + ci * 8 + (lm & 7)] = (bf16)e;
                lrs[mt][i] += e;
            }
        }
    };

    auto phaseB = [&](int kt, int buf) {
        #pragma unroll
        for (int kk2 = 0; kk2 < 2; ++kk2) {
            bf16x8 p[2][2], bv[4];
            #pragma unroll
            for (int a2 = 0; a2 < 2; ++a2)
                #pragma unroll
                for (int mt = 0; mt < 2; ++mt)
                    p[a2][mt] = *(const bf16x8*)(P + (((buf * 2 + a2) * 2 + mt) * 2 + kk2) * 512
                                                   + lm * 32 + ciq8);
            #pragma unroll
            for (int nt = 0; nt < 4; ++nt)
                bv[nt] = *(const bf16x8*)(Vt + ((size_t)((d0 >> 4) + nt) * 256 + (kt >> 5) + kk2) * 512
                                            + lm * 32 + lk8);
            #pragma unroll
            for (int a2 = 0; a2 < 2; ++a2)
                #pragma unroll
                for (int mt = 0; mt < 2; ++mt)
                    #pragma unroll
                    for (int nt = 0; nt < 4; ++nt)
                        O[a2][mt][nt] = MFMA16(p[a2][mt], bv[nt], O[a2][mt][nt]);
        }
    };

    phaseA(k0, 0);
    __syncthreads();
    for (int it = 0; it < NITER; ++it) {
        int cur = it & 1;
        phaseB(k0 + it * KTILE, cur);                          // operands ready: run first
        if (it + 1 < NITER) phaseA(k0 + (it + 1) * KTILE, cur ^ 1);
        __syncthreads();
    }

    // one-time lsum reduction
    #pragma unroll
    for (int mt = 0; mt < 2; ++mt)
        #pragma unroll
        for (int i = 0; i < 4; ++i) {
            float v = lrs[mt][i];
            v += __shfl_xor(v, 1); v += __shfl_xor(v, 2);
            v += __shfl_xor(v, 4); v += __shfl_xor(v, 8);
            if (lm == 0) atomicAdd(&lsum[pa_a][mt * 16 + r0 + i], v);
        }

    // epilogue: stage O via LDS, nontemporal full-line stores
    #pragma unroll
    for (int a2 = 0; a2 < 2; ++a2) {
        __syncthreads();
        #pragma unroll
        for (int mt = 0; mt < 2; ++mt)
            #pragma unroll
            for (int nt = 0; nt < 4; ++nt)
                #pragma unroll
                for (int i = 0; i < 4; ++i) {
                    int r = mt * 16 + r0 + i;
                    int c = d0 + nt * 16 + lm;
                    int c8s = ((c >> 3) ^ ((r >> 2) & 3)) * 8;
                    Qs[r * 512 + c8s + (c & 7)] = (bf16)O[a2][mt][nt][i];
                }
        __syncthreads();
        bf16* Op = Opart + (size_t)(2 * split + a2) * NROWS * 512 + (size_t)q0 * 512;
        #pragma unroll
        for (int j = 0; j < 4; ++j) {
            int ch = tid + 512 * j;
            int r = ch >> 6;
            int c8 = ch & 63;
            intx4 v = *(const intx4*)(Qs + r * 512 + ((c8 ^ ((r >> 2) & 3)) * 8));
            __builtin_nontemporal_store(v, (intx4*)(Op + ch * 8));
        }
    }
    if (tid < 64)
        Lpart[(size_t)(2 * split + (tid >> 5)) * NROWS + q0 + (tid & 31)] = lsum[tid >> 5][tid & 31];
}

// ---------------- combine: sum splits, normalize, gate (w1 bf16) ----------------
__global__ void combine_kernel(const bf16* __restrict__ Opart, const float* __restrict__ Lpart,
                               const bf16* __restrict__ W1, float* __restrict__ out, int n4) {
    int i = blockIdx.x * blockDim.x + threadIdx.x;
    if (i >= n4) return;
    int q = i >> 7;
    float l1 = 0.f, l2 = 0.f;
    #pragma unroll
    for (int s = 0; s < NSPLIT; ++s) {
        l1 += Lpart[(size_t)(2 * s + 0) * NROWS + q];
        l2 += Lpart[(size_t)(2 * s + 1) * NROWS + q];
    }
    float o1[4] = {0.f, 0.f, 0.f, 0.f}, o2[4] = {0.f, 0.f, 0.f, 0.f};
    #pragma unroll
    for (int s = 0; s < NSPLIT; ++s) {
        bf16x4 v1 = ((const bf16x4*)(Opart + (size_t)(2 * s + 0) * NROWS * 512))[i];
        bf16x4 v2 = ((const bf16x4*)(Opart + (size_t)(2 * s + 1) * NROWS * 512))[i];
        #pragma unroll
        for (int j = 0; j < 4; ++j) { o1[j] += (float)v1[j]; o2[j] += (float)v2[j]; }
    }
    bf16x4 wv = ((const bf16x4*)W1)[i];
    float4 r;
    float rl1 = 1.f / l1, rl2 = 1.f / l2;
    {
        float w0 = (float)wv[0], w1_ = (float)wv[1], w2 = (float)wv[2], w3 = (float)wv[3];
        r.x = w0 * (o1[0] * rl1) + (1.f - w0) * (o2[0] * rl2);
        r.y = w1_ * (o1[1] * rl1) + (1.f - w1_) * (o2[1] * rl2);
        r.z = w2 * (o1[2] * rl1) + (1.f - w2) * (o2[2] * rl2);
        r.w = w3 * (o1[3] * rl1) + (1.f - w3) * (o2[3] * rl2);
    }
    ((float4*)out)[i] = r;
}

// ---------------- host launch ----------------
extern "C" void kernel_launch(void* const* d_in, const int* in_sizes, int n_in,
                              void* d_out, int out_size, void* d_ws, size_t ws_size,
                              hipStream_t stream) {
    const float* sp   = (const float*)d_in[0];
    const float* om1  = (const float*)d_in[1];
    const float* om2  = (const float*)d_in[2];
    const float* q_w  = (const float*)d_in[3];
    const float* q_b  = (const float*)d_in[4];
    const float* k1_w = (const float*)d_in[5];
    const float* k1_b = (const float*)d_in[6];
    const float* k2_w = (const float*)d_in[7];
    const float* k2_b = (const float*)d_in[8];
    const float* v_w  = (const float*)d_in[9];
    const float* v_b  = (const float*)d_in[10];
    const float* c1_w = (const float*)d_in[11];
    const float* c1_b = (const float*)d_in[12];
    float* out = (float*)d_out;

    char* ws = (char*)d_ws;
    size_t off = 0;
    auto alloc = [&](size_t bytes) -> void* {
        void* p = ws + off;
        off += (bytes + 255) & ~(size_t)255;
        return p;
    };
    const size_t NM = (size_t)NROWS * DCH;

    // persistent region (blocked layouts)
    bf16* Q    = (bf16*)alloc(NM * 2);
    bf16* K1   = (bf16*)alloc(NM * 2);
    bf16* K2   = (bf16*)alloc(NM * 2);
    bf16* Vt   = (bf16*)alloc(NM * 2);
    bf16* W1g  = (bf16*)alloc(NM * 2);   // gate weights, bf16 row-major

    // temp region (dead after conf_gemm) — overlaid by Opart/Lpart
    size_t mark = off;
    bf16* spb  = (bf16*)alloc(NM * 2);
    bf16* om1b = (bf16*)alloc(NM * 2);
    bf16* om2b = (bf16*)alloc(NM * 2);
    bf16* qwb  = (bf16*)alloc(512 * 512 * 2);
    bf16* k1wb = (bf16*)alloc(512 * 512 * 2);
    bf16* k2wb = (bf16*)alloc(512 * 512 * 2);
    bf16* vwb  = (bf16*)alloc(512 * 1536 * 2);
    bf16* c1wb = (bf16*)alloc(512 * 1024 * 2);

    off = mark;
    bf16*  Opart = (bf16*)alloc((size_t)2 * NSPLIT * NM * 2);
    float* Lpart = (float*)alloc((size_t)2 * NSPLIT * NROWS * 4);

    // ---- single merged convert launch ----
    CvtArgs ca;
    ca.src[0] = sp;   ca.dst[0] = spb;  ca.C[0] = 512;  ca.n8[0] = NROWS * 512 / 8; ca.scale[0] = 1.f;
    ca.src[1] = om1;  ca.dst[1] = om1b; ca.C[1] = 512;  ca.n8[1] = NROWS * 512 / 8; ca.scale[1] = 1.f;
    ca.src[2] = om2;  ca.dst[2] = om2b; ca.C[2] = 512;  ca.n8[2] = NROWS * 512 / 8; ca.scale[2] = 1.f;
    ca.src[3] = q_w;  ca.dst[3] = qwb;  ca.C[3] = 512;  ca.n8[3] = 512 * 512 / 8;   ca.scale[3] = PRESCALE;
    ca.src[4] = k1_w; ca.dst[4] = k1wb; ca.C[4] = 512;  ca.n8[4] = 512 * 512 / 8;   ca.scale[4] = 1.f;
    ca.src[5] = k2_w; ca.dst[5] = k2wb; ca.C[5] = 512;  ca.n8[5] = 512 * 512 / 8;   ca.scale[5] = 1.f;
    ca.src[6] = v_w;  ca.dst[6] = vwb;  ca.C[6] = 1536; ca.n8[6] = 512 * 1536 / 8;  ca.scale[6] = 1.f;
    ca.src[7] = c1_w; ca.dst[7] = c1wb; ca.C[7] = 1024; ca.n8[7] = 512 * 1024 / 8;  ca.scale[7] = 1.f;
    {
        int maxb = (NROWS * 512 / 8 + 255) / 256;
        dim3 cgrid(maxb, 8);
        cvt_all_kernel<<<cgrid, 256, 0, stream>>>(ca);
    }

    // ---- projections (Q, K1, K2, Vt) ----
    dim3 pgrid(512 / 128, NROWS / 128, 4);
    proj_gemm<<<pgrid, 256, 0, stream>>>(spb, om1b, om2b, qwb, k1wb, k2wb, vwb,
                                         q_b, k1_b, k2_b, v_b, Q, K1, K2, Vt);

    // ---- conf + gate fused ----
    dim3 cfgrid(512 / 128, NROWS / 128);
    conf_gemm<<<cfgrid, 256, 0, stream>>>(spb, om1b, om2b, c1wb, c1_b, W1g);

    // ---- attention ----
    attn_kernel<<<(NROWS / 32) * NSPLIT, 512, 0, stream>>>(Q, K1, K2, Vt, Opart, Lpart);

    // ---- combine ----
    int n4 = (int)(NM / 4);
    combine_kernel<<<(n4 + 255) / 256, 256, 0, stream>>>(Opart, Lpart, W1g, out, n4);
}